// Round 1
// baseline (386.423 us; speedup 1.0000x reference)
//
#include <hip/hip_runtime.h>
#include <hip/hip_bf16.h>
#include <math.h>

// ---------------------------------------------------------------------------
// UpdateAttn: decoder block = QKV proj -> MHA (no mask) -> Wo + res + LN1
//             -> Wff + res + LN2 -> 2*out + pos_emb(batch)
// S=2048 B=2 D=1024 H=16 DH=64.  All GEMMs bf16 MFMA; residual/LN in f32.
// ---------------------------------------------------------------------------

typedef __bf16 bf16x8 __attribute__((ext_vector_type(8)));
typedef float f32x4  __attribute__((ext_vector_type(4)));

typedef const __attribute__((address_space(1))) unsigned int as1_uint;
typedef __attribute__((address_space(3))) unsigned int as3_uint;

constexpr int S_SEQ = 2048;
constexpr int NB    = 2;
constexpr int DM    = 1024;
constexpr int NH    = 16;
constexpr int DH    = 64;
constexpr int MROWS = S_SEQ * NB;       // 4096
constexpr float SM_SCALE = 0.125f;      // 1/sqrt(64)

#define WS_MB (1ull << 20)

__device__ __forceinline__ void gload16(void* lds, const void* g) {
  __builtin_amdgcn_global_load_lds((as1_uint*)g, (as3_uint*)lds, 16, 0, 0);
}

// -------------------------- f32 -> bf16 convert ----------------------------
__global__ void cvt_f32_bf16(const float* __restrict__ in,
                             __hip_bfloat16* __restrict__ out, int n4) {
  int idx = blockIdx.x * blockDim.x + threadIdx.x;
  if (idx >= n4) return;
  float4 v = ((const float4*)in)[idx];
  __hip_bfloat16 tmp[4];
  tmp[0] = __float2bfloat16(v.x);
  tmp[1] = __float2bfloat16(v.y);
  tmp[2] = __float2bfloat16(v.z);
  tmp[3] = __float2bfloat16(v.w);
  *(uint2*)(out + (size_t)idx * 4) = *(uint2*)tmp;
}

// ------------------------------ pos table ----------------------------------
// pe[pos][2k] = sin(pos*f_k), pe[pos][2k+1] = cos(pos*f_k), f_k = 10000^(-2k/1024)
__global__ void pe_kernel(float* __restrict__ pe) {
  int k = blockIdx.x * blockDim.x + threadIdx.x;
  if (k >= 512) return;
  float freq = expf(-(2.0f * (float)k / 1024.0f) * logf(10000.0f));
  pe[2 * k]          = 0.0f;          // pos 0: sin(0)
  pe[2 * k + 1]      = 1.0f;          // pos 0: cos(0)
  pe[1024 + 2 * k]     = sinf(freq);  // pos 1
  pe[1024 + 2 * k + 1] = cosf(freq);
}

// ------------------------------ GEMM (B^T) ---------------------------------
// C[m][n] = sum_k A[m][k] * Bw[n][k].  A,Bw bf16 row-major.
// MODE 0: write C f32 row-major.
// MODE 1: QKV scatter: n<1024 -> Q[b][h][i][dh]; n<2048 -> K same; else V^T[b][h][dh][i]
template <int MODE>
__global__ __launch_bounds__(256)
void gemm_bt(const __hip_bfloat16* __restrict__ A,
             const __hip_bfloat16* __restrict__ Bw,
             float* __restrict__ C,
             __hip_bfloat16* __restrict__ Qb,
             __hip_bfloat16* __restrict__ Kb,
             __hip_bfloat16* __restrict__ VTb,
             int Ndim, int Kdim) {
  constexpr int BK = 64;
  __shared__ __hip_bfloat16 sA[128 * BK];
  __shared__ __hip_bfloat16 sB[128 * BK];
  const int t = threadIdx.x, w = t >> 6, l = t & 63;
  const int bm = blockIdx.y * 128, bn = blockIdx.x * 128;
  const int m0 = (w >> 1) * 64, n0 = (w & 1) * 64;
  const int lrow = l >> 3, lcol = l & 7;   // staging: 8 rows x 8 col-chunks per wave-load
  const int ll = l & 15, lg = l >> 4;

  f32x4 acc[4][4] = {};

  for (int kt = 0; kt < Kdim; kt += BK) {
    __syncthreads();
#pragma unroll
    for (int r = 0; r < 4; ++r) {
      const int chunk = r * 4 + w;               // 16 chunks of 8 rows
      const int row = chunk * 8 + lrow;
      gload16((char*)sA + chunk * 1024 + l * 16,
              A + (size_t)(bm + row) * Kdim + kt + lcol * 8);
      gload16((char*)sB + chunk * 1024 + l * 16,
              Bw + (size_t)(bn + row) * Kdim + kt + lcol * 8);
    }
    __syncthreads();
#pragma unroll
    for (int ks = 0; ks < 2; ++ks) {
      bf16x8 a[4], b[4];
#pragma unroll
      for (int mi = 0; mi < 4; ++mi)
        a[mi] = *(const bf16x8*)((const char*)sA +
                 (m0 + mi * 16 + ll) * 128 + ks * 64 + lg * 16);
#pragma unroll
      for (int ni = 0; ni < 4; ++ni)
        b[ni] = *(const bf16x8*)((const char*)sB +
                 (n0 + ni * 16 + ll) * 128 + ks * 64 + lg * 16);
#pragma unroll
      for (int mi = 0; mi < 4; ++mi)
#pragma unroll
        for (int ni = 0; ni < 4; ++ni)
          acc[mi][ni] = __builtin_amdgcn_mfma_f32_16x16x32_bf16(
              a[mi], b[ni], acc[mi][ni], 0, 0, 0);
    }
  }

#pragma unroll
  for (int mi = 0; mi < 4; ++mi)
#pragma unroll
    for (int ni = 0; ni < 4; ++ni)
#pragma unroll
      for (int r = 0; r < 4; ++r) {
        const int gm = bm + m0 + mi * 16 + lg * 4 + r;
        const int gn = bn + n0 + ni * 16 + ll;
        const float v = acc[mi][ni][r];
        if (MODE == 0) {
          C[(size_t)gm * Ndim + gn] = v;
        } else {
          const int i = gm >> 1, bb = gm & 1;
          const __hip_bfloat16 hv = __float2bfloat16(v);
          if (gn < 1024) {
            const int h = gn >> 6, dh = gn & 63;
            Qb[(((size_t)(bb * 16 + h)) * 2048 + i) * 64 + dh] = hv;
          } else if (gn < 2048) {
            const int e = gn - 1024, h = e >> 6, dh = e & 63;
            Kb[(((size_t)(bb * 16 + h)) * 2048 + i) * 64 + dh] = hv;
          } else {
            const int e = gn - 2048, h = e >> 6, dh = e & 63;
            VTb[(((size_t)(bb * 16 + h)) * 64 + dh) * 2048 + i] = hv;
          }
        }
      }
}

// ----------------------------- flash attention ------------------------------
// grid.x = q-tile (32 tiles of 64 rows), grid.y = bh (32).  4 waves/block,
// each wave owns 16 q rows.  32 kv per iter: QK^T (4 MFMA) -> online softmax
// (16-lane shfl reduces) -> P via per-wave LDS -> PV (4 MFMA vs V^T).
__global__ __launch_bounds__(256)
void attn_kernel(const __hip_bfloat16* __restrict__ Qb,
                 const __hip_bfloat16* __restrict__ Kb,
                 const __hip_bfloat16* __restrict__ VTb,
                 __hip_bfloat16* __restrict__ vec) {
  __shared__ __hip_bfloat16 pl[4][16][32];
  const int t = threadIdx.x, w = t >> 6, l = t & 63;
  const int qt = blockIdx.x, bh = blockIdx.y;
  const int b = bh >> 4, h = bh & 15;
  const __hip_bfloat16* Q  = Qb + (size_t)bh * S_SEQ * DH;
  const __hip_bfloat16* K  = Kb + (size_t)bh * S_SEQ * DH;
  const __hip_bfloat16* VT = VTb + (size_t)bh * DH * S_SEQ;
  const int ll = l & 15, lg = l >> 4;

  const int qrow = qt * 64 + w * 16 + ll;
  bf16x8 qf0 = *(const bf16x8*)(Q + (size_t)qrow * 64 + lg * 8);
  bf16x8 qf1 = *(const bf16x8*)(Q + (size_t)qrow * 64 + 32 + lg * 8);

  float m_run[4] = {-INFINITY, -INFINITY, -INFINITY, -INFINITY};
  float l_run[4] = {0.f, 0.f, 0.f, 0.f};
  f32x4 oacc[4] = {};

  for (int j0 = 0; j0 < S_SEQ; j0 += 32) {
    f32x4 s0 = {0.f, 0.f, 0.f, 0.f}, s1 = {0.f, 0.f, 0.f, 0.f};
    bf16x8 k00 = *(const bf16x8*)(K + (size_t)(j0 + ll) * 64 + lg * 8);
    bf16x8 k01 = *(const bf16x8*)(K + (size_t)(j0 + ll) * 64 + 32 + lg * 8);
    bf16x8 k10 = *(const bf16x8*)(K + (size_t)(j0 + 16 + ll) * 64 + lg * 8);
    bf16x8 k11 = *(const bf16x8*)(K + (size_t)(j0 + 16 + ll) * 64 + 32 + lg * 8);
    s0 = __builtin_amdgcn_mfma_f32_16x16x32_bf16(qf0, k00, s0, 0, 0, 0);
    s0 = __builtin_amdgcn_mfma_f32_16x16x32_bf16(qf1, k01, s0, 0, 0, 0);
    s1 = __builtin_amdgcn_mfma_f32_16x16x32_bf16(qf0, k10, s1, 0, 0, 0);
    s1 = __builtin_amdgcn_mfma_f32_16x16x32_bf16(qf1, k11, s1, 0, 0, 0);

    float cm[4];
#pragma unroll
    for (int r = 0; r < 4; ++r) {
      s0[r] *= SM_SCALE; s1[r] *= SM_SCALE;
      cm[r] = fmaxf(s0[r], s1[r]);
    }
#pragma unroll
    for (int off = 1; off < 16; off <<= 1)
#pragma unroll
      for (int r = 0; r < 4; ++r) cm[r] = fmaxf(cm[r], __shfl_xor(cm[r], off));

    float alpha[4], rs[4];
#pragma unroll
    for (int r = 0; r < 4; ++r) {
      const float nm = fmaxf(m_run[r], cm[r]);
      alpha[r] = __expf(m_run[r] - nm);
      m_run[r] = nm;
      s0[r] = __expf(s0[r] - nm);
      s1[r] = __expf(s1[r] - nm);
      rs[r] = s0[r] + s1[r];
    }
#pragma unroll
    for (int off = 1; off < 16; off <<= 1)
#pragma unroll
      for (int r = 0; r < 4; ++r) rs[r] += __shfl_xor(rs[r], off);
#pragma unroll
    for (int r = 0; r < 4; ++r) l_run[r] = l_run[r] * alpha[r] + rs[r];
#pragma unroll
    for (int df = 0; df < 4; ++df)
#pragma unroll
      for (int r = 0; r < 4; ++r) oacc[df][r] *= alpha[r];

#pragma unroll
    for (int r = 0; r < 4; ++r) {
      pl[w][lg * 4 + r][ll]      = __float2bfloat16(s0[r]);
      pl[w][lg * 4 + r][16 + ll] = __float2bfloat16(s1[r]);
    }
    bf16x8 pa = *(const bf16x8*)&pl[w][ll][lg * 8];
#pragma unroll
    for (int df = 0; df < 4; ++df) {
      bf16x8 vf = *(const bf16x8*)(VT + (size_t)(df * 16 + ll) * S_SEQ + j0 + lg * 8);
      oacc[df] = __builtin_amdgcn_mfma_f32_16x16x32_bf16(pa, vf, oacc[df], 0, 0, 0);
    }
  }

  float inv[4];
#pragma unroll
  for (int r = 0; r < 4; ++r) inv[r] = 1.0f / l_run[r];
  const int i0 = qt * 64 + w * 16 + lg * 4;
#pragma unroll
  for (int df = 0; df < 4; ++df)
#pragma unroll
    for (int r = 0; r < 4; ++r) {
      const int e = h * 64 + df * 16 + ll;
      vec[((size_t)(i0 + r) * 2 + b) * 1024 + e] =
          __float2bfloat16(oacc[df][r] * inv[r]);
    }
}

// --------------------- residual add + LayerNorm (fused) ---------------------
__global__ __launch_bounds__(256)
void add_ln_kernel(const float* __restrict__ X, const float* __restrict__ Yadd,
                   const float* __restrict__ g, const float* __restrict__ bb,
                   float* __restrict__ out_f32,
                   __hip_bfloat16* __restrict__ out_b16) {
  const int row = blockIdx.x, t = threadIdx.x;
  const float4 x4 = *(const float4*)(X + (size_t)row * 1024 + t * 4);
  const float4 a4 = *(const float4*)(Yadd + (size_t)row * 1024 + t * 4);
  float v[4] = {x4.x + a4.x, x4.y + a4.y, x4.z + a4.z, x4.w + a4.w};
  float s = v[0] + v[1] + v[2] + v[3];
  float s2 = v[0] * v[0] + v[1] * v[1] + v[2] * v[2] + v[3] * v[3];
#pragma unroll
  for (int off = 1; off < 64; off <<= 1) {
    s += __shfl_xor(s, off);
    s2 += __shfl_xor(s2, off);
  }
  __shared__ float rs[4], rs2[4];
  if ((t & 63) == 0) { rs[t >> 6] = s; rs2[t >> 6] = s2; }
  __syncthreads();
  const float tot = rs[0] + rs[1] + rs[2] + rs[3];
  const float tot2 = rs2[0] + rs2[1] + rs2[2] + rs2[3];
  const float mu = tot * (1.0f / 1024.0f);
  const float var = tot2 * (1.0f / 1024.0f) - mu * mu;
  const float rstd = rsqrtf(var + 1e-5f);
  const float4 g4 = *(const float4*)(g + t * 4);
  const float4 b4 = *(const float4*)(bb + t * 4);
  float y[4];
  y[0] = (v[0] - mu) * rstd * g4.x + b4.x;
  y[1] = (v[1] - mu) * rstd * g4.y + b4.y;
  y[2] = (v[2] - mu) * rstd * g4.z + b4.z;
  y[3] = (v[3] - mu) * rstd * g4.w + b4.w;
  *(float4*)(out_f32 + (size_t)row * 1024 + t * 4) =
      make_float4(y[0], y[1], y[2], y[3]);
  __hip_bfloat16 tmp[4] = {__float2bfloat16(y[0]), __float2bfloat16(y[1]),
                           __float2bfloat16(y[2]), __float2bfloat16(y[3])};
  *(uint2*)(out_b16 + (size_t)row * 1024 + t * 4) = *(uint2*)tmp;
}

// ---------------- residual add + LayerNorm + 2*y + pe (final) ---------------
__global__ __launch_bounds__(256)
void final_kernel(const float* __restrict__ X, const float* __restrict__ Yadd,
                  const float* __restrict__ g, const float* __restrict__ bb,
                  const float* __restrict__ pe, float* __restrict__ out) {
  const int row = blockIdx.x, t = threadIdx.x;
  const float4 x4 = *(const float4*)(X + (size_t)row * 1024 + t * 4);
  const float4 a4 = *(const float4*)(Yadd + (size_t)row * 1024 + t * 4);
  float v[4] = {x4.x + a4.x, x4.y + a4.y, x4.z + a4.z, x4.w + a4.w};
  float s = v[0] + v[1] + v[2] + v[3];
  float s2 = v[0] * v[0] + v[1] * v[1] + v[2] * v[2] + v[3] * v[3];
#pragma unroll
  for (int off = 1; off < 64; off <<= 1) {
    s += __shfl_xor(s, off);
    s2 += __shfl_xor(s2, off);
  }
  __shared__ float rs[4], rs2[4];
  if ((t & 63) == 0) { rs[t >> 6] = s; rs2[t >> 6] = s2; }
  __syncthreads();
  const float tot = rs[0] + rs[1] + rs[2] + rs[3];
  const float tot2 = rs2[0] + rs2[1] + rs2[2] + rs2[3];
  const float mu = tot * (1.0f / 1024.0f);
  const float var = tot2 * (1.0f / 1024.0f) - mu * mu;
  const float rstd = rsqrtf(var + 1e-5f);
  const float4 g4 = *(const float4*)(g + t * 4);
  const float4 b4 = *(const float4*)(bb + t * 4);
  const int bidx = row & 1;
  const float4 p4 = *(const float4*)(pe + bidx * 1024 + t * 4);
  float y[4];
  y[0] = 2.0f * ((v[0] - mu) * rstd * g4.x + b4.x) + p4.x;
  y[1] = 2.0f * ((v[1] - mu) * rstd * g4.y + b4.y) + p4.y;
  y[2] = 2.0f * ((v[2] - mu) * rstd * g4.z + b4.z) + p4.z;
  y[3] = 2.0f * ((v[3] - mu) * rstd * g4.w + b4.w) + p4.w;
  *(float4*)(out + (size_t)row * 1024 + t * 4) = make_float4(y[0], y[1], y[2], y[3]);
}

// ---------------------------------------------------------------------------
extern "C" void kernel_launch(void* const* d_in, const int* in_sizes, int n_in,
                              void* d_out, int out_size, void* d_ws,
                              size_t ws_size, hipStream_t stream) {
  const float* x   = (const float*)d_in[0];
  const float* Wq  = (const float*)d_in[1];
  const float* Wkv = (const float*)d_in[2];
  const float* Wo  = (const float*)d_in[3];
  const float* g1  = (const float*)d_in[4];
  const float* b1  = (const float*)d_in[5];
  const float* Wff = (const float*)d_in[6];
  const float* g2  = (const float*)d_in[7];
  const float* b2  = (const float*)d_in[8];

  char* ws = (char*)d_ws;
  // bf16 weights: [Wq | Wkv] stacked (3072x1024), Wo, Wff
  __hip_bfloat16* Wqkv_b = (__hip_bfloat16*)(ws + 0);          // 6 MB
  __hip_bfloat16* Wo_b   = (__hip_bfloat16*)(ws + 6 * WS_MB);  // 2 MB
  __hip_bfloat16* Wff_b  = (__hip_bfloat16*)(ws + 8 * WS_MB);  // 2 MB
  __hip_bfloat16* Xb     = (__hip_bfloat16*)(ws + 10 * WS_MB); // 8 MB
  __hip_bfloat16* Qb     = (__hip_bfloat16*)(ws + 18 * WS_MB); // 8 MB
  __hip_bfloat16* Kb     = (__hip_bfloat16*)(ws + 26 * WS_MB); // 8 MB
  __hip_bfloat16* VTb    = (__hip_bfloat16*)(ws + 34 * WS_MB); // 8 MB
  __hip_bfloat16* vecb   = (__hip_bfloat16*)(ws + 42 * WS_MB); // 8 MB
  float* attn            = (float*)(ws + 18 * WS_MB);          // 16 MB (alias Q+K, dead)
  float* out1            = (float*)(ws + 50 * WS_MB);          // 16 MB
  __hip_bfloat16* out1b  = (__hip_bfloat16*)(ws + 66 * WS_MB); // 8 MB
  float* ffb             = (float*)(ws + 34 * WS_MB);          // 16 MB (alias VT+vec, dead)
  float* pe              = (float*)(ws + 74 * WS_MB);          // 8 KB

  // 1) casts + pos table
  cvt_f32_bf16<<<4096, 256, 0, stream>>>(x, Xb, 1048576);
  cvt_f32_bf16<<<1024, 256, 0, stream>>>(Wq, Wqkv_b, 262144);
  cvt_f32_bf16<<<2048, 256, 0, stream>>>(Wkv, Wqkv_b + 1024 * 1024, 524288);
  cvt_f32_bf16<<<1024, 256, 0, stream>>>(Wo, Wo_b, 262144);
  cvt_f32_bf16<<<1024, 256, 0, stream>>>(Wff, Wff_b, 262144);
  pe_kernel<<<1, 512, 0, stream>>>(pe);

  // 2) QKV projection (M=4096, N=3072, K=1024), scatter to Q/K/V^T bf16
  gemm_bt<1><<<dim3(24, 32), 256, 0, stream>>>(Xb, Wqkv_b, nullptr, Qb, Kb, VTb,
                                               3072, 1024);
  // 3) flash attention -> vec bf16 [S*B][1024]
  attn_kernel<<<dim3(32, 32), 256, 0, stream>>>(Qb, Kb, VTb, vecb);
  // 4) Wo projection -> attn f32
  gemm_bt<0><<<dim3(8, 32), 256, 0, stream>>>(vecb, Wo_b, attn, nullptr, nullptr,
                                              nullptr, 1024, 1024);
  // 5) out1 = LN(x + attn)
  add_ln_kernel<<<4096, 256, 0, stream>>>(x, attn, g1, b1, out1, out1b);
  // 6) ff = out1 @ Wff^T
  gemm_bt<0><<<dim3(8, 32), 256, 0, stream>>>(out1b, Wff_b, ffb, nullptr, nullptr,
                                              nullptr, 1024, 1024);
  // 7) out = 2*LN(out1 + ff) + pe[b]
  final_kernel<<<4096, 256, 0, stream>>>(out1, ffb, g2, b2, pe, (float*)d_out);
}